// Round 7
// baseline (44.890 us; speedup 1.0000x reference)
//
#include <hip/hip_runtime.h>
#include <hip/hip_bf16.h>
#include <math.h>

#define S_SAMPLED 1000
#define SPAD      1024
#define DIM       512
#define BATCH     8192

#define BM 128
#define BN 256
#define BKT 64                 // K per tile (128 B bf16, 256 B f32)
#define KTILES (DIM / BKT)     // 8
#define NCHUNK 4               // SPAD / BN
#define GEMM_BLOCKS 256
#define M0C 20.0f              // fixed softmax max bound (logits <= ~8; HW-verified r5/r6)

typedef __attribute__((ext_vector_type(8))) short short8_t;  // 8 bf16
typedef __attribute__((ext_vector_type(4))) float f32x4_t;

__device__ __forceinline__ float neg_log_expected(int c) {
    const float log_vp1 = 11.5129354649f;   // log(100001)
    float p = log1pf(1.0f / (float)(c + 1)) / log_vp1;
    float E = -expm1f((float)S_SAMPLED * log1pf(-p));
    return -logf(E);
}

__device__ __forceinline__ unsigned short f2bf(float x) {
    __hip_bfloat16 h = __float2bfloat16(x);
    union { __hip_bfloat16 h; unsigned short u; } cv; cv.h = h; return cv.u;
}

__device__ __forceinline__ void load_lds16(const void* g, void* l) {
    __builtin_amdgcn_global_load_lds(
        (const __attribute__((address_space(1))) void*)g,
        (__attribute__((address_space(3))) void*)l, 16, 0, 0);
}

// involution on byte addr: bits 4-6 ^= row&7 (rows are 128B apart)
__device__ __forceinline__ int swz(int lin) { return lin ^ (((lin >> 7) & 7) << 4); }

// ------------- kernel 0: prep (no y_pred cast anymore) ----------------------
// blocks 0..511   : gather+cast W[sampled] -> Wg bf16, compute adj (2 rows/blk)
// blocks 512..2559: true logits f32 (4 rows/blk)  [also warms L3 with y_pred]
__global__ __launch_bounds__(256) void prep_kernel(
    const int* __restrict__ y_true, const float* __restrict__ y_pred,
    const float* __restrict__ W, const float* __restrict__ b,
    const int* __restrict__ sampled,
    unsigned short* __restrict__ Wg, float* __restrict__ adj,
    float* __restrict__ true_out, int* __restrict__ counter)
{
    int bid = blockIdx.x;
    if (bid == 0 && threadIdx.x == 0) *counter = 0;
    if (bid < 512) {
        int row = bid * 2 + (threadIdx.x >> 7);   // 0..1023
        int t   = threadIdx.x & 127;              // 128 threads * 4 elems
        if (t == 0) {
            if (row < S_SAMPLED) {
                int c = sampled[row];
                adj[row] = b[c] + neg_log_expected(c);
            } else adj[row] = -1e30f;
        }
        unsigned short* dst = Wg + (size_t)row * DIM + t * 4;
        if (row < S_SAMPLED) {
            float4 f = *(const float4*)(W + (size_t)sampled[row] * DIM + t * 4);
            ushort4 o;
            o.x = f2bf(f.x); o.y = f2bf(f.y); o.z = f2bf(f.z); o.w = f2bf(f.w);
            *(ushort4*)dst = o;
        } else {
            *(ushort4*)dst = make_ushort4(0, 0, 0, 0);
        }
    } else {
        int row  = (bid - 512) * 4 + (threadIdx.x >> 6);
        int lane = threadIdx.x & 63;
        int lab  = y_true[row];
        const float4* ap = (const float4*)(y_pred + (size_t)row * DIM);
        const float4* wp = (const float4*)(W + (size_t)lab * DIM);
        float s = 0.f;
#pragma unroll
        for (int u = 0; u < 2; ++u) {
            float4 a = ap[lane + u * 64];
            float4 w = wp[lane + u * 64];
            s += a.x * w.x + a.y * w.y + a.z * w.z + a.w * w.w;
        }
#pragma unroll
        for (int off = 32; off; off >>= 1) s += __shfl_xor(s, off);
        if (lane == 0) true_out[row] = s + b[lab] + neg_log_expected(lab);
    }
}

// ------------- kernel 1: MFMA GEMM (A from f32 direct) + LSE + finalize -----
// 1-D grid 256 blocks (XCD-swizzled), 512 threads = 8 waves (4 Mwaves x 2 Nwaves)
// A: reg-staged f32 -> cvt bf16 -> swizzled ds_write. B: global_load_lds bf16.
__global__ __launch_bounds__(512, 2) void gemm_partial_kernel(
    const float* __restrict__ Ay,             // y_pred f32 [BATCH][DIM] (L3-hot)
    const unsigned short* __restrict__ Wg,    // gathered W bf16 [SPAD][DIM]
    const int*   __restrict__ sampled,
    const float* __restrict__ adj,
    const int*   __restrict__ y_true,
    const float* __restrict__ true_v,         // [BATCH]
    float*       __restrict__ psum,           // [BATCH][NCHUNK]
    int*         __restrict__ counter,
    float*       __restrict__ out)
{
    __shared__ __align__(16) char smem[98304 + 2048];
    __shared__ int s_last;
    char* As0 = smem;                              // 16 KB
    char* As1 = smem + 16384;
    char* Bs0 = smem + 32768;                      // 32 KB
    char* Bs1 = smem + 65536;
    float* reds = (float*)(smem + 98304);          // [2][128]

    // XCD-aware remap: all 4 n-chunks of an m-stripe on one XCD
    int wg = blockIdx.x;
    int sw = (wg & 7) * 32 + (wg >> 3);     // bijective, 256 blocks
    const int m0    = (sw >> 2) * BM;
    const int chunk = sw & 3;
    const int n0    = chunk * BN;

    const int tid  = threadIdx.x;
    const int lane = tid & 63;
    const int wid  = tid >> 6;
    const int wr   = wid >> 1;
    const int wc   = wid & 1;
    const int g    = lane >> 4;
    const int lcol = lane & 15;

    const char* WB = (const char*)Wg;

    // ---- A reg-staging addresses: thread covers 16 f32 (64B) of one row ----
    const int arow = tid >> 2;                              // 0..127
    const char* a_ptr = (const char*)Ay
        + (size_t)(m0 + arow) * (DIM * 4) + (tid & 3) * 64;
    const int asl0 = arow * 128 + (((tid & 3) * 32) ^ ((arow & 7) << 4));
    const int asl1 = asl0 ^ 16;

    // ---- B staging sources: linear LDS dest, source pre-inverse-swizzled ---
    int b_src[4];
#pragma unroll
    for (int it = 0; it < 4; ++it) {
        int d = it * 8192 + tid * 16;
        int col = d >> 7;
        int kb  = (d & 127) ^ ((col & 7) << 4);
        b_src[it] = (n0 + col) * (DIM * 2) + kb;
    }

    int a_roff[2][2], b_roff[8][2];
#pragma unroll
    for (int mi = 0; mi < 2; ++mi)
#pragma unroll
        for (int ks = 0; ks < 2; ++ks)
            a_roff[mi][ks] = swz((wr * 32 + mi * 16 + lcol) * 128 + ks * 64 + g * 16);
#pragma unroll
    for (int nj = 0; nj < 8; ++nj)
#pragma unroll
        for (int ks = 0; ks < 2; ++ks)
            b_roff[nj][ks] = swz((wc * 128 + nj * 16 + lcol) * 128 + ks * 64 + g * 16);

    f32x4_t acc[2][8] = {};
    float4  av[2][4];   // A reg double-buffer (indices literal after unroll)

#define A_LOAD(pb, kt) do {                                          \
        const float4* p_ = (const float4*)(a_ptr + (kt) * 256);      \
        av[pb][0] = p_[0]; av[pb][1] = p_[1];                        \
        av[pb][2] = p_[2]; av[pb][3] = p_[3];                        \
    } while (0)

#define A_WRITE(AsP, pb) do {                                        \
        uint4 o0_, o1_;                                              \
        o0_.x = (unsigned)f2bf(av[pb][0].x) | ((unsigned)f2bf(av[pb][0].y) << 16); \
        o0_.y = (unsigned)f2bf(av[pb][0].z) | ((unsigned)f2bf(av[pb][0].w) << 16); \
        o0_.z = (unsigned)f2bf(av[pb][1].x) | ((unsigned)f2bf(av[pb][1].y) << 16); \
        o0_.w = (unsigned)f2bf(av[pb][1].z) | ((unsigned)f2bf(av[pb][1].w) << 16); \
        o1_.x = (unsigned)f2bf(av[pb][2].x) | ((unsigned)f2bf(av[pb][2].y) << 16); \
        o1_.y = (unsigned)f2bf(av[pb][2].z) | ((unsigned)f2bf(av[pb][2].w) << 16); \
        o1_.z = (unsigned)f2bf(av[pb][3].x) | ((unsigned)f2bf(av[pb][3].y) << 16); \
        o1_.w = (unsigned)f2bf(av[pb][3].z) | ((unsigned)f2bf(av[pb][3].w) << 16); \
        *(uint4*)((AsP) + asl0) = o0_;                               \
        *(uint4*)((AsP) + asl1) = o1_;                               \
    } while (0)

#define STAGE_B(BsP, kt) do {                                        \
        int kb_ = (kt) * 128;                                        \
        load_lds16(WB + b_src[0] + kb_, (BsP) + tid * 16);           \
        load_lds16(WB + b_src[1] + kb_, (BsP) + 8192 + tid * 16);    \
        load_lds16(WB + b_src[2] + kb_, (BsP) + 16384 + tid * 16);   \
        load_lds16(WB + b_src[3] + kb_, (BsP) + 24576 + tid * 16);   \
    } while (0)

#define COMPUTE(AsP, BsP) do {                                                        \
        _Pragma("unroll")                                                             \
        for (int ks = 0; ks < 2; ++ks) {                                              \
            short8_t a0 = *(const short8_t*)((AsP) + a_roff[0][ks]);                  \
            short8_t a1 = *(const short8_t*)((AsP) + a_roff[1][ks]);                  \
            _Pragma("unroll")                                                         \
            for (int nj = 0; nj < 8; ++nj) {                                          \
                short8_t bv = *(const short8_t*)((BsP) + b_roff[nj][ks]);             \
                acc[0][nj] = __builtin_amdgcn_mfma_f32_16x16x32_bf16(a0, bv, acc[0][nj], 0, 0, 0); \
                acc[1][nj] = __builtin_amdgcn_mfma_f32_16x16x32_bf16(a1, bv, acc[1][nj], 0, 0, 0); \
            }                                                                         \
        }                                                                             \
    } while (0)

    // ---- K loop: mixed counted-wait pipeline, never vmcnt(0) mid-loop ----
    // Per-wave FIFO at top of iter t: [A(t)4, B(t)4, A(t+1)4, B(t+1)4] = 16.
    __builtin_amdgcn_sched_barrier(0);
    A_LOAD(0, 0); STAGE_B(Bs0, 0);
    A_LOAD(1, 1); STAGE_B(Bs1, 1);
#pragma unroll
    for (int t = 0; t < KTILES; ++t) {
        char* AsC = (t & 1) ? As1 : As0;
        char* BsC = (t & 1) ? Bs1 : Bs0;
        if (t < KTILES - 1) asm volatile("s_waitcnt vmcnt(12)" ::: "memory");
        else                asm volatile("s_waitcnt vmcnt(4)"  ::: "memory");
        A_WRITE(AsC, t & 1);     // own A(t) regs -> swizzled LDS
        if (t < KTILES - 1) asm volatile("s_waitcnt vmcnt(8) lgkmcnt(0)" ::: "memory");
        else                asm volatile("s_waitcnt vmcnt(0) lgkmcnt(0)" ::: "memory");
        __builtin_amdgcn_s_barrier();
        __builtin_amdgcn_sched_barrier(0);
        __builtin_amdgcn_s_setprio(1);
        COMPUTE(AsC, BsC);
        __builtin_amdgcn_s_setprio(0);
        __builtin_amdgcn_sched_barrier(0);
        __builtin_amdgcn_s_barrier();
        if (t + 2 < KTILES) { A_LOAD(t & 1, t + 2); STAGE_B(BsC, t + 2); }
    }
    __builtin_amdgcn_sched_barrier(0);

    // ---- epilogue: adj + hit mask, fixed-max partial sum of exp(x - M0) ----
    // C layout: col = lane&15, row = (lane>>4)*4 + r
    int   labs[2][4];
    float srow[2][4];
#pragma unroll
    for (int mi = 0; mi < 2; ++mi)
#pragma unroll
        for (int r = 0; r < 4; ++r) {
            labs[mi][r] = y_true[m0 + wr * 32 + mi * 16 + g * 4 + r];
            srow[mi][r] = 0.f;
        }

    float ajv[8]; int scv[8];
#pragma unroll
    for (int nj = 0; nj < 8; ++nj) {
        int cg = n0 + wc * 128 + nj * 16 + lcol;
        ajv[nj] = adj[cg];
        scv[nj] = (cg < S_SAMPLED) ? sampled[cg] : -2147483647;
    }

#pragma unroll
    for (int mi = 0; mi < 2; ++mi)
#pragma unroll
        for (int nj = 0; nj < 8; ++nj) {
#pragma unroll
            for (int r = 0; r < 4; ++r) {
                float x = acc[mi][nj][r] + ajv[nj];
                if (scv[nj] == labs[mi][r]) x -= 1e9f;
                srow[mi][r] += expf(x - M0C);   // hit/pad -> exp(-huge) = 0
            }
        }

#pragma unroll
    for (int s = 1; s < 16; s <<= 1)
#pragma unroll
        for (int mi = 0; mi < 2; ++mi)
#pragma unroll
            for (int r = 0; r < 4; ++r)
                srow[mi][r] += __shfl_xor(srow[mi][r], s);
    if (lcol == 0) {
#pragma unroll
        for (int mi = 0; mi < 2; ++mi)
#pragma unroll
            for (int r = 0; r < 4; ++r)
                reds[wc * 128 + wr * 32 + mi * 16 + g * 4 + r] = srow[mi][r];
    }
    __syncthreads();

    if (tid < BM)
        psum[(size_t)(m0 + tid) * NCHUNK + chunk] = reds[tid] + reds[128 + tid];

    // ---- completion counting; last block merges partials and writes mean ----
    __syncthreads();
    if (tid == 0) {
        __threadfence();                       // release: psum visible
        int old = atomicAdd(counter, 1);
        s_last = (old == GEMM_BLOCKS - 1) ? 1 : 0;
    }
    __syncthreads();
    if (!s_last) return;

    __threadfence();                           // acquire
    float tot = 0.f;
#pragma unroll
    for (int i = 0; i < BATCH / 512; ++i) {
        int r = tid + i * 512;
        float4 ps = *(const float4*)(psum + (size_t)r * NCHUNK);
        float t = true_v[r];
        float s = ps.x + ps.y + ps.z + ps.w + expf(t - M0C);
        tot += logf(s) + M0C - t;
    }
    float* red = (float*)smem;
    red[tid] = tot;
    __syncthreads();
    for (int st = 256; st; st >>= 1) {
        if (tid < st) red[tid] += red[tid + st];
        __syncthreads();
    }
    if (tid == 0) out[0] = red[0] / (float)BATCH;
#undef A_LOAD
#undef A_WRITE
#undef STAGE_B
#undef COMPUTE
}

extern "C" void kernel_launch(void* const* d_in, const int* in_sizes, int n_in,
                              void* d_out, int out_size, void* d_ws, size_t ws_size,
                              hipStream_t stream) {
    const int*   y_true  = (const int*)d_in[0];
    const float* y_pred  = (const float*)d_in[1];
    const float* W       = (const float*)d_in[2];
    const float* b       = (const float*)d_in[3];
    const int*   sampled = (const int*)d_in[4];

    char* ws = (char*)d_ws;
    unsigned short* Wg = (unsigned short*)ws;                     // 1 MB
    float* adj     = (float*)(ws + 1048576);                      // 4 KB
    float* true_v  = (float*)(ws + 1052672);                      // 32 KB
    float* psum    = (float*)(ws + 1085440);                      // 128 KB
    int*   counter = (int*)(ws + 1216512);                        // 4 B

    prep_kernel<<<2560, 256, 0, stream>>>(y_true, y_pred, W, b, sampled,
                                          Wg, adj, true_v, counter);
    gemm_partial_kernel<<<GEMM_BLOCKS, 512, 0, stream>>>(
        y_pred, Wg, sampled, adj, y_true, true_v, psum, counter, (float*)d_out);
}

// Round 8
// 34.087 us; speedup vs baseline: 1.3169x; 1.3169x over previous
//
#include <hip/hip_runtime.h>
#include <hip/hip_bf16.h>
#include <math.h>

#define S_SAMPLED 1000
#define SPAD      1024
#define DIM       512
#define BATCH     8192

#define BM 128
#define BN 128
#define BKT 64                 // K per tile (128 B bf16)
#define KTILES (DIM / BKT)     // 8
#define NCHUNK 8               // SPAD / BN
#define GEMM_BLOCKS 512        // (BATCH/BM) * NCHUNK
#define M0C 20.0f              // fixed softmax max bound (HW-verified exact r5/r6)

typedef __attribute__((ext_vector_type(8))) short short8_t;  // 8 bf16
typedef __attribute__((ext_vector_type(4))) float f32x4_t;

__device__ __forceinline__ float neg_log_expected(int c) {
    const float log_vp1 = 11.5129354649f;   // log(100001)
    float p = log1pf(1.0f / (float)(c + 1)) / log_vp1;
    float E = -expm1f((float)S_SAMPLED * log1pf(-p));
    return -logf(E);
}

__device__ __forceinline__ unsigned short f2bf(float x) {
    __hip_bfloat16 h = __float2bfloat16(x);
    union { __hip_bfloat16 h; unsigned short u; } cv; cv.h = h; return cv.u;
}

__device__ __forceinline__ void load_lds16(const void* g, void* l) {
    __builtin_amdgcn_global_load_lds(
        (const __attribute__((address_space(1))) void*)g,
        (__attribute__((address_space(3))) void*)l, 16, 0, 0);
}

// involution on byte addr: bits 4-6 ^= row&7 (rows are 128B apart)
__device__ __forceinline__ int swz(int lin) { return lin ^ (((lin >> 7) & 7) << 4); }

// ------------- kernel 0: fused prep (identical to round 4) ------------------
// blocks 0..511   : gather+cast W[sampled] -> Wg bf16, compute adj (2 rows/blk)
// blocks 512..2559: true logits (f32) + cast y_pred -> bf16 (4 rows/blk)
__global__ __launch_bounds__(256) void prep_kernel(
    const int* __restrict__ y_true, const float* __restrict__ y_pred,
    const float* __restrict__ W, const float* __restrict__ b,
    const int* __restrict__ sampled,
    unsigned short* __restrict__ Wg, float* __restrict__ adj,
    float* __restrict__ true_out, unsigned short* __restrict__ ypredB)
{
    int bid = blockIdx.x;
    if (bid < 512) {
        int row = bid * 2 + (threadIdx.x >> 7);   // 0..1023
        int t   = threadIdx.x & 127;              // 128 threads * 4 elems
        if (t == 0) {
            if (row < S_SAMPLED) {
                int c = sampled[row];
                adj[row] = b[c] + neg_log_expected(c);
            } else adj[row] = -1e30f;
        }
        unsigned short* dst = Wg + (size_t)row * DIM + t * 4;
        if (row < S_SAMPLED) {
            float4 f = *(const float4*)(W + (size_t)sampled[row] * DIM + t * 4);
            ushort4 o;
            o.x = f2bf(f.x); o.y = f2bf(f.y); o.z = f2bf(f.z); o.w = f2bf(f.w);
            *(ushort4*)dst = o;
        } else {
            *(ushort4*)dst = make_ushort4(0, 0, 0, 0);
        }
    } else {
        int row  = (bid - 512) * 4 + (threadIdx.x >> 6);
        int lane = threadIdx.x & 63;
        int lab  = y_true[row];
        const float4* ap = (const float4*)(y_pred + (size_t)row * DIM);
        const float4* wp = (const float4*)(W + (size_t)lab * DIM);
        float s = 0.f;
#pragma unroll
        for (int u = 0; u < 2; ++u) {
            float4 a = ap[lane + u * 64];
            float4 w = wp[lane + u * 64];
            s += a.x * w.x + a.y * w.y + a.z * w.z + a.w * w.w;
            ushort4 o;
            o.x = f2bf(a.x); o.y = f2bf(a.y); o.z = f2bf(a.z); o.w = f2bf(a.w);
            *(ushort4*)(ypredB + (size_t)row * DIM + (lane + u * 64) * 4) = o;
        }
#pragma unroll
        for (int off = 32; off; off >>= 1) s += __shfl_xor(s, off);
        if (lane == 0) true_out[row] = s + b[lab] + neg_log_expected(lab);
    }
}

// ------------- kernel 1: MFMA GEMM + fixed-max partial sums -----------------
// BM=128 x BN=128, LDS 66KB -> 2 blocks/CU. 512 threads = 8 waves (4M x 2N).
// Grid 512, XCD-swizzled so each XCD owns 8 complete m-stripes.
__global__ __launch_bounds__(512, 4) void gemm_partial_kernel(
    const unsigned short* __restrict__ Abf,   // y_pred bf16 [BATCH][DIM]
    const unsigned short* __restrict__ Wg,    // gathered W bf16 [SPAD][DIM]
    const int*   __restrict__ sampled,
    const float* __restrict__ adj,
    const int*   __restrict__ y_true,
    float*       __restrict__ psum)           // [BATCH][NCHUNK]
{
    __shared__ __align__(16) char smem[65536 + 1024];
    char* As0 = smem;                              // 16 KB
    char* As1 = smem + 16384;
    char* Bs0 = smem + 32768;                      // 16 KB
    char* Bs1 = smem + 49152;
    float* reds = (float*)(smem + 65536);          // [2][128]

    // XCD-aware remap: XCD i gets sw 64i..64i+63 = stripes 8i..8i+7, all chunks
    int wg = blockIdx.x;
    int sw = (wg & 7) * 64 + (wg >> 3);     // bijective, 512 blocks
    const int m0    = (sw >> 3) * BM;
    const int chunk = sw & 7;
    const int n0    = chunk * BN;

    const int tid  = threadIdx.x;
    const int lane = tid & 63;
    const int wid  = tid >> 6;
    const int wr   = wid >> 1;
    const int wc   = wid & 1;
    const int g    = lane >> 4;
    const int lcol = lane & 15;

    const char* AB = (const char*)Abf;
    const char* WB = (const char*)Wg;

    // staging: linear LDS dest (tid*16), source pre-inverse-swizzled (rule #21)
    int a_src[2], b_src[2];
#pragma unroll
    for (int it = 0; it < 2; ++it) {
        int d = it * 8192 + tid * 16;
        int row = d >> 7;
        int kb  = (d & 127) ^ ((row & 7) << 4);
        a_src[it] = (m0 + row) * (DIM * 2) + kb;
        b_src[it] = (n0 + row) * (DIM * 2) + kb;
    }

    int a_roff[2][2], b_roff[4][2];
#pragma unroll
    for (int mi = 0; mi < 2; ++mi)
#pragma unroll
        for (int ks = 0; ks < 2; ++ks)
            a_roff[mi][ks] = swz((wr * 32 + mi * 16 + lcol) * 128 + ks * 64 + g * 16);
#pragma unroll
    for (int nj = 0; nj < 4; ++nj)
#pragma unroll
        for (int ks = 0; ks < 2; ++ks)
            b_roff[nj][ks] = swz((wc * 64 + nj * 16 + lcol) * 128 + ks * 64 + g * 16);

    f32x4_t acc[2][4] = {};

#define STAGE(AsP, BsP, kt) do {                                     \
        int kb_ = (kt) * 128;                                        \
        load_lds16(AB + a_src[0] + kb_, (AsP) + tid * 16);           \
        load_lds16(AB + a_src[1] + kb_, (AsP) + 8192 + tid * 16);    \
        load_lds16(WB + b_src[0] + kb_, (BsP) + tid * 16);           \
        load_lds16(WB + b_src[1] + kb_, (BsP) + 8192 + tid * 16);    \
    } while (0)

#define COMPUTE(AsP, BsP) do {                                                        \
        _Pragma("unroll")                                                             \
        for (int ks = 0; ks < 2; ++ks) {                                              \
            short8_t a0 = *(const short8_t*)((AsP) + a_roff[0][ks]);                  \
            short8_t a1 = *(const short8_t*)((AsP) + a_roff[1][ks]);                  \
            _Pragma("unroll")                                                         \
            for (int nj = 0; nj < 4; ++nj) {                                          \
                short8_t bv = *(const short8_t*)((BsP) + b_roff[nj][ks]);             \
                acc[0][nj] = __builtin_amdgcn_mfma_f32_16x16x32_bf16(a0, bv, acc[0][nj], 0, 0, 0); \
                acc[1][nj] = __builtin_amdgcn_mfma_f32_16x16x32_bf16(a1, bv, acc[1][nj], 0, 0, 0); \
            }                                                                         \
        }                                                                             \
    } while (0)

    // ---- K loop: counted-vmcnt double-buffer (T3/T4), raw barriers ----
    __builtin_amdgcn_sched_barrier(0);
    STAGE(As0, Bs0, 0);
    STAGE(As1, Bs1, 1);
#pragma unroll
    for (int t = 0; t < KTILES; ++t) {
        if (t < KTILES - 1) asm volatile("s_waitcnt vmcnt(4)" ::: "memory");
        else                asm volatile("s_waitcnt vmcnt(0)" ::: "memory");
        __builtin_amdgcn_s_barrier();
        __builtin_amdgcn_sched_barrier(0);
        const char* AsP = (t & 1) ? As1 : As0;
        const char* BsP = (t & 1) ? Bs1 : Bs0;
        __builtin_amdgcn_s_setprio(1);
        COMPUTE(AsP, BsP);
        __builtin_amdgcn_s_setprio(0);
        __builtin_amdgcn_sched_barrier(0);
        __builtin_amdgcn_s_barrier();
        if (t + 2 < KTILES) STAGE((t & 1) ? As1 : As0, (t & 1) ? Bs1 : Bs0, t + 2);
    }
    __builtin_amdgcn_sched_barrier(0);

    // ---- epilogue: adj + hit mask, fixed-max partial sum of exp(x - M0) ----
    // C layout: col = lane&15, row = (lane>>4)*4 + r
    int   labs[2][4];
    float srow[2][4];
#pragma unroll
    for (int mi = 0; mi < 2; ++mi)
#pragma unroll
        for (int r = 0; r < 4; ++r) {
            labs[mi][r] = y_true[m0 + wr * 32 + mi * 16 + g * 4 + r];
            srow[mi][r] = 0.f;
        }

    float ajv[4]; int scv[4];
#pragma unroll
    for (int nj = 0; nj < 4; ++nj) {
        int cg = n0 + wc * 64 + nj * 16 + lcol;
        ajv[nj] = adj[cg];
        scv[nj] = (cg < S_SAMPLED) ? sampled[cg] : -2147483647;
    }

#pragma unroll
    for (int mi = 0; mi < 2; ++mi)
#pragma unroll
        for (int nj = 0; nj < 4; ++nj) {
#pragma unroll
            for (int r = 0; r < 4; ++r) {
                float x = acc[mi][nj][r] + ajv[nj];
                if (scv[nj] == labs[mi][r]) x -= 1e9f;
                srow[mi][r] += expf(x - M0C);   // hit/pad -> exp(-huge) = 0
            }
        }

#pragma unroll
    for (int s = 1; s < 16; s <<= 1)
#pragma unroll
        for (int mi = 0; mi < 2; ++mi)
#pragma unroll
            for (int r = 0; r < 4; ++r)
                srow[mi][r] += __shfl_xor(srow[mi][r], s);
    if (lcol == 0) {
#pragma unroll
        for (int mi = 0; mi < 2; ++mi)
#pragma unroll
            for (int r = 0; r < 4; ++r)
                reds[wc * 128 + wr * 32 + mi * 16 + g * 4 + r] = srow[mi][r];
    }
    __syncthreads();

    if (tid < BM)
        psum[(size_t)(m0 + tid) * NCHUNK + chunk] = reds[tid] + reds[128 + tid];
#undef STAGE
#undef COMPUTE
}

// ------------- kernel 2: merge partials + mean (single block) ---------------
__global__ __launch_bounds__(1024) void finalize_kernel(
    const float* __restrict__ psum, const float* __restrict__ true_v,
    float* __restrict__ out)
{
    __shared__ float sm[1024];
    float tot = 0.f;
#pragma unroll
    for (int u = 0; u < BATCH / 1024; ++u) {
        int r = u * 1024 + threadIdx.x;
        float4 p0 = *(const float4*)(psum + (size_t)r * NCHUNK);
        float4 p1 = *(const float4*)(psum + (size_t)r * NCHUNK + 4);
        float t = true_v[r];
        float s = p0.x + p0.y + p0.z + p0.w
                + p1.x + p1.y + p1.z + p1.w + expf(t - M0C);
        tot += logf(s) + M0C - t;
    }
    sm[threadIdx.x] = tot;
    __syncthreads();
    for (int st = 512; st; st >>= 1) {
        if (threadIdx.x < st) sm[threadIdx.x] += sm[threadIdx.x + st];
        __syncthreads();
    }
    if (threadIdx.x == 0) out[0] = sm[0] / (float)BATCH;
}

extern "C" void kernel_launch(void* const* d_in, const int* in_sizes, int n_in,
                              void* d_out, int out_size, void* d_ws, size_t ws_size,
                              hipStream_t stream) {
    const int*   y_true  = (const int*)d_in[0];
    const float* y_pred  = (const float*)d_in[1];
    const float* W       = (const float*)d_in[2];
    const float* b       = (const float*)d_in[3];
    const int*   sampled = (const int*)d_in[4];

    char* ws = (char*)d_ws;
    unsigned short* ypredB = (unsigned short*)ws;                 // 8 MB
    unsigned short* Wg     = (unsigned short*)(ws + 8388608);     // 1 MB
    float* adj    = (float*)(ws + 9437184);                       // 4 KB
    float* true_v = (float*)(ws + 9441280);                       // 32 KB
    float* psum   = (float*)(ws + 9474048);                       // 256 KB

    prep_kernel<<<2560, 256, 0, stream>>>(y_true, y_pred, W, b, sampled,
                                          Wg, adj, true_v, ypredB);
    gemm_partial_kernel<<<GEMM_BLOCKS, 512, 0, stream>>>(
        ypredB, Wg, sampled, adj, y_true, psum);
    finalize_kernel<<<1, 1024, 0, stream>>>(psum, true_v, (float*)d_out);
}

// Round 9
// 33.626 us; speedup vs baseline: 1.3350x; 1.0137x over previous
//
#include <hip/hip_runtime.h>
#include <hip/hip_bf16.h>
#include <math.h>

#define S_SAMPLED 1000
#define SPAD      1024
#define DIM       512
#define BATCH     8192

#define BM 128
#define BN 128
#define BKT 64                 // K per tile (128 B bf16)
#define KTILES (DIM / BKT)     // 8
#define NCHUNK 8               // SPAD / BN
#define GEMM_BLOCKS 512        // (BATCH/BM) * NCHUNK
#define FIN_BLOCKS 8
#define M0C 20.0f              // fixed softmax max bound (HW-verified exact r5/r6/r8)

typedef __attribute__((ext_vector_type(8))) short short8_t;  // 8 bf16
typedef __attribute__((ext_vector_type(4))) float f32x4_t;

__device__ __forceinline__ float neg_log_expected(int c) {
    const float log_vp1 = 11.5129354649f;   // log(100001)
    float p = log1pf(1.0f / (float)(c + 1)) / log_vp1;
    float E = -expm1f((float)S_SAMPLED * log1pf(-p));
    return -logf(E);
}

__device__ __forceinline__ unsigned short f2bf(float x) {
    __hip_bfloat16 h = __float2bfloat16(x);
    union { __hip_bfloat16 h; unsigned short u; } cv; cv.h = h; return cv.u;
}

__device__ __forceinline__ float b2f(short u) {
    union { float f; unsigned u; } c;
    c.u = ((unsigned)(unsigned short)u) << 16;
    return c.f;
}

__device__ __forceinline__ void load_lds16(const void* g, void* l) {
    __builtin_amdgcn_global_load_lds(
        (const __attribute__((address_space(1))) void*)g,
        (__attribute__((address_space(3))) void*)l, 16, 0, 0);
}

// involution on byte addr: bits 4-6 ^= row&7 (rows are 128B apart)
__device__ __forceinline__ int swz(int lin) { return lin ^ (((lin >> 7) & 7) << 4); }

// ------------- kernel 0: prep ------------------------------------------------
// blocks 0..511   : gather+cast W[sampled] -> Wg bf16, compute adj (2 rows/blk)
// blocks 512..2559: pure cast y_pred f32 -> bf16 (2048 elems/blk)
__global__ __launch_bounds__(256) void prep_kernel(
    const float* __restrict__ y_pred, const float* __restrict__ W,
    const float* __restrict__ b, const int* __restrict__ sampled,
    unsigned short* __restrict__ Wg, float* __restrict__ adj,
    unsigned short* __restrict__ ypredB, int* __restrict__ counter)
{
    int bid = blockIdx.x;
    if (bid == 0 && threadIdx.x == 0) *counter = 0;
    if (bid < 512) {
        int row = bid * 2 + (threadIdx.x >> 7);   // 0..1023
        int t   = threadIdx.x & 127;              // 128 threads * 4 elems
        if (t == 0) {
            if (row < S_SAMPLED) {
                int c = sampled[row];
                adj[row] = b[c] + neg_log_expected(c);
            } else adj[row] = -1e30f;
        }
        unsigned short* dst = Wg + (size_t)row * DIM + t * 4;
        if (row < S_SAMPLED) {
            float4 f = *(const float4*)(W + (size_t)sampled[row] * DIM + t * 4);
            ushort4 o;
            o.x = f2bf(f.x); o.y = f2bf(f.y); o.z = f2bf(f.z); o.w = f2bf(f.w);
            *(ushort4*)dst = o;
        } else {
            *(ushort4*)dst = make_ushort4(0, 0, 0, 0);
        }
    } else {
        int i = (bid - 512) * 2048 + threadIdx.x * 8;
        float4 f0 = *(const float4*)(y_pred + i);
        float4 f1 = *(const float4*)(y_pred + i + 4);
        uint4 o;
        o.x = (unsigned)f2bf(f0.x) | ((unsigned)f2bf(f0.y) << 16);
        o.y = (unsigned)f2bf(f0.z) | ((unsigned)f2bf(f0.w) << 16);
        o.z = (unsigned)f2bf(f1.x) | ((unsigned)f2bf(f1.y) << 16);
        o.w = (unsigned)f2bf(f1.z) | ((unsigned)f2bf(f1.w) << 16);
        *(uint4*)(ypredB + i) = o;
    }
}

// ------------- kernel 1: MFMA GEMM + partial sums + true logits -------------
// BM=128 x BN=128, LDS 66KB -> 2 blocks/CU. 512 threads = 8 waves (4M x 2N).
// Grid 512, XCD-swizzled so each XCD owns 8 complete m-stripes.
// Chunk block c of stripe s also computes true logits for rows m0+16c..+15.
__global__ __launch_bounds__(512, 4) void gemm_partial_kernel(
    const unsigned short* __restrict__ Abf,   // y_pred bf16 [BATCH][DIM]
    const unsigned short* __restrict__ Wg,    // gathered W bf16 [SPAD][DIM]
    const int*   __restrict__ sampled,
    const float* __restrict__ adj,
    const int*   __restrict__ y_true,
    const float* __restrict__ W,              // f32, for true-logit gather
    const float* __restrict__ b,
    float*       __restrict__ true_v,         // [BATCH]
    float*       __restrict__ psum)           // [BATCH][NCHUNK]
{
    __shared__ __align__(16) char smem[65536 + 1024];
    char* As0 = smem;                              // 16 KB
    char* As1 = smem + 16384;
    char* Bs0 = smem + 32768;                      // 16 KB
    char* Bs1 = smem + 49152;
    float* reds = (float*)(smem + 65536);          // [2][128]

    // XCD-aware remap: XCD i gets sw 64i..64i+63 = stripes 8i..8i+7, all chunks
    int wg = blockIdx.x;
    int sw = (wg & 7) * 64 + (wg >> 3);     // bijective, 512 blocks
    const int m0    = (sw >> 3) * BM;
    const int chunk = sw & 7;
    const int n0    = chunk * BN;

    const int tid  = threadIdx.x;
    const int lane = tid & 63;
    const int wid  = tid >> 6;
    const int wr   = wid >> 1;
    const int wc   = wid & 1;
    const int g    = lane >> 4;
    const int lcol = lane & 15;

    const char* AB = (const char*)Abf;
    const char* WB = (const char*)Wg;

    // staging: linear LDS dest (tid*16), source pre-inverse-swizzled (rule #21)
    int a_src[2], b_src[2];
#pragma unroll
    for (int it = 0; it < 2; ++it) {
        int d = it * 8192 + tid * 16;
        int row = d >> 7;
        int kb  = (d & 127) ^ ((row & 7) << 4);
        a_src[it] = (m0 + row) * (DIM * 2) + kb;
        b_src[it] = (n0 + row) * (DIM * 2) + kb;
    }

    int a_roff[2][2], b_roff[4][2];
#pragma unroll
    for (int mi = 0; mi < 2; ++mi)
#pragma unroll
        for (int ks = 0; ks < 2; ++ks)
            a_roff[mi][ks] = swz((wr * 32 + mi * 16 + lcol) * 128 + ks * 64 + g * 16);
#pragma unroll
    for (int nj = 0; nj < 4; ++nj)
#pragma unroll
        for (int ks = 0; ks < 2; ++ks)
            b_roff[nj][ks] = swz((wc * 64 + nj * 16 + lcol) * 128 + ks * 64 + g * 16);

    f32x4_t acc[2][4] = {};

#define STAGE(AsP, BsP, kt) do {                                     \
        int kb_ = (kt) * 128;                                        \
        load_lds16(AB + a_src[0] + kb_, (AsP) + tid * 16);           \
        load_lds16(AB + a_src[1] + kb_, (AsP) + 8192 + tid * 16);    \
        load_lds16(WB + b_src[0] + kb_, (BsP) + tid * 16);           \
        load_lds16(WB + b_src[1] + kb_, (BsP) + 8192 + tid * 16);    \
    } while (0)

#define COMPUTE(AsP, BsP) do {                                                        \
        _Pragma("unroll")                                                             \
        for (int ks = 0; ks < 2; ++ks) {                                              \
            short8_t a0 = *(const short8_t*)((AsP) + a_roff[0][ks]);                  \
            short8_t a1 = *(const short8_t*)((AsP) + a_roff[1][ks]);                  \
            _Pragma("unroll")                                                         \
            for (int nj = 0; nj < 4; ++nj) {                                          \
                short8_t bv = *(const short8_t*)((BsP) + b_roff[nj][ks]);             \
                acc[0][nj] = __builtin_amdgcn_mfma_f32_16x16x32_bf16(a0, bv, acc[0][nj], 0, 0, 0); \
                acc[1][nj] = __builtin_amdgcn_mfma_f32_16x16x32_bf16(a1, bv, acc[1][nj], 0, 0, 0); \
            }                                                                         \
        }                                                                             \
    } while (0)

    // ---- K loop: counted-vmcnt double-buffer (T3/T4), raw barriers ----
    __builtin_amdgcn_sched_barrier(0);
    STAGE(As0, Bs0, 0);
    STAGE(As1, Bs1, 1);
#pragma unroll
    for (int t = 0; t < KTILES; ++t) {
        if (t < KTILES - 1) asm volatile("s_waitcnt vmcnt(4)" ::: "memory");
        else                asm volatile("s_waitcnt vmcnt(0)" ::: "memory");
        __builtin_amdgcn_s_barrier();
        __builtin_amdgcn_sched_barrier(0);
        const char* AsP = (t & 1) ? As1 : As0;
        const char* BsP = (t & 1) ? Bs1 : Bs0;
        __builtin_amdgcn_s_setprio(1);
        COMPUTE(AsP, BsP);
        __builtin_amdgcn_s_setprio(0);
        __builtin_amdgcn_sched_barrier(0);
        __builtin_amdgcn_s_barrier();
        if (t + 2 < KTILES) STAGE((t & 1) ? As1 : As0, (t & 1) ? Bs1 : Bs0, t + 2);
    }
    __builtin_amdgcn_sched_barrier(0);

    // ---- true logits for this block's 16 rows (2 rows/wave) ----
    // bf16 y_pred (L2-hot) x f32 W[label], f32 accumulate.
#pragma unroll
    for (int rr = 0; rr < 2; ++rr) {
        int row = m0 + chunk * 16 + wid * 2 + rr;
        int lab = y_true[row];
        short8_t a8 = *(const short8_t*)(Abf + (size_t)row * DIM + lane * 8);
        float4 w0 = *(const float4*)(W + (size_t)lab * DIM + lane * 8);
        float4 w1 = *(const float4*)(W + (size_t)lab * DIM + lane * 8 + 4);
        float s = b2f(a8[0]) * w0.x + b2f(a8[1]) * w0.y
                + b2f(a8[2]) * w0.z + b2f(a8[3]) * w0.w
                + b2f(a8[4]) * w1.x + b2f(a8[5]) * w1.y
                + b2f(a8[6]) * w1.z + b2f(a8[7]) * w1.w;
#pragma unroll
        for (int off = 32; off; off >>= 1) s += __shfl_xor(s, off);
        if (lane == 0) true_v[row] = s + b[lab] + neg_log_expected(lab);
    }

    // ---- epilogue: adj + hit mask, fixed-max partial sum of exp(x - M0) ----
    // C layout: col = lane&15, row = (lane>>4)*4 + r
    int   labs[2][4];
    float srow[2][4];
#pragma unroll
    for (int mi = 0; mi < 2; ++mi)
#pragma unroll
        for (int r = 0; r < 4; ++r) {
            labs[mi][r] = y_true[m0 + wr * 32 + mi * 16 + g * 4 + r];
            srow[mi][r] = 0.f;
        }

    float ajv[4]; int scv[4];
#pragma unroll
    for (int nj = 0; nj < 4; ++nj) {
        int cg = n0 + wc * 64 + nj * 16 + lcol;
        ajv[nj] = adj[cg];
        scv[nj] = (cg < S_SAMPLED) ? sampled[cg] : -2147483647;
    }

#pragma unroll
    for (int mi = 0; mi < 2; ++mi)
#pragma unroll
        for (int nj = 0; nj < 4; ++nj) {
#pragma unroll
            for (int r = 0; r < 4; ++r) {
                float x = acc[mi][nj][r] + ajv[nj];
                if (scv[nj] == labs[mi][r]) x -= 1e9f;
                srow[mi][r] += expf(x - M0C);   // hit/pad -> exp(-huge) = 0
            }
        }

#pragma unroll
    for (int s = 1; s < 16; s <<= 1)
#pragma unroll
        for (int mi = 0; mi < 2; ++mi)
#pragma unroll
            for (int r = 0; r < 4; ++r)
                srow[mi][r] += __shfl_xor(srow[mi][r], s);
    if (lcol == 0) {
#pragma unroll
        for (int mi = 0; mi < 2; ++mi)
#pragma unroll
            for (int r = 0; r < 4; ++r)
                reds[wc * 128 + wr * 32 + mi * 16 + g * 4 + r] = srow[mi][r];
    }
    __syncthreads();

    if (tid < BM)
        psum[(size_t)(m0 + tid) * NCHUNK + chunk] = reds[tid] + reds[128 + tid];
#undef STAGE
#undef COMPUTE
}

// ------------- kernel 2: parallel finalize (8 blocks + counter tail) --------
__global__ __launch_bounds__(1024) void finalize_kernel(
    const float* __restrict__ psum, const float* __restrict__ true_v,
    float* __restrict__ partial, int* __restrict__ counter,
    float* __restrict__ out)
{
    __shared__ float sm[1024];
    __shared__ int s_last;
    int r = blockIdx.x * 1024 + threadIdx.x;
    float4 p0 = *(const float4*)(psum + (size_t)r * NCHUNK);
    float4 p1 = *(const float4*)(psum + (size_t)r * NCHUNK + 4);
    float t = true_v[r];
    float s = p0.x + p0.y + p0.z + p0.w
            + p1.x + p1.y + p1.z + p1.w + expf(t - M0C);
    sm[threadIdx.x] = logf(s) + M0C - t;
    __syncthreads();
    for (int st = 512; st; st >>= 1) {
        if (threadIdx.x < st) sm[threadIdx.x] += sm[threadIdx.x + st];
        __syncthreads();
    }
    if (threadIdx.x == 0) {
        partial[blockIdx.x] = sm[0];
        __threadfence();
        int old = atomicAdd(counter, 1);
        s_last = (old == FIN_BLOCKS - 1) ? 1 : 0;
    }
    __syncthreads();
    if (!s_last || threadIdx.x != 0) return;
    __threadfence();
    float tot = 0.f;
#pragma unroll
    for (int i = 0; i < FIN_BLOCKS; ++i) tot += partial[i];
    out[0] = tot / (float)BATCH;
}

extern "C" void kernel_launch(void* const* d_in, const int* in_sizes, int n_in,
                              void* d_out, int out_size, void* d_ws, size_t ws_size,
                              hipStream_t stream) {
    const int*   y_true  = (const int*)d_in[0];
    const float* y_pred  = (const float*)d_in[1];
    const float* W       = (const float*)d_in[2];
    const float* b       = (const float*)d_in[3];
    const int*   sampled = (const int*)d_in[4];

    char* ws = (char*)d_ws;
    unsigned short* ypredB = (unsigned short*)ws;                 // 8 MB
    unsigned short* Wg     = (unsigned short*)(ws + 8388608);     // 1 MB
    float* adj     = (float*)(ws + 9437184);                      // 4 KB
    float* true_v  = (float*)(ws + 9441280);                      // 32 KB
    float* psum    = (float*)(ws + 9474048);                      // 256 KB
    float* partial = (float*)(ws + 9736192);                      // 32 B
    int*   counter = (int*)(ws + 9736256);                        // 4 B

    prep_kernel<<<2560, 256, 0, stream>>>(y_pred, W, b, sampled,
                                          Wg, adj, ypredB, counter);
    gemm_partial_kernel<<<GEMM_BLOCKS, 512, 0, stream>>>(
        ypredB, Wg, sampled, adj, y_true, W, b, true_v, psum);
    finalize_kernel<<<FIN_BLOCKS, 1024, 0, stream>>>(
        psum, true_v, partial, counter, (float*)d_out);
}